// Round 1
// baseline (33.946 us; speedup 1.0000x reference)
//
#include <hip/hip_runtime.h>

#define TPB 256

// Pade-13 coefficients (cast to float32, matching reference `b = _PADE_B.astype(A.dtype)`)
#define B0  6.476475253248e+16f
#define B1  3.238237626624e+16f
#define B2  7.7717703038976e+15f
#define B3  1.1873537964288e+15f
#define B4  1.29060195264e+14f
#define B5  1.05594705216e+13f
#define B6  6.704425728e+11f
#define B7  3.352212864e+10f
#define B8  1.32324192e+9f
#define B9  4.08408e+7f
#define B10 9.6096e+5f
#define B11 1.638e+4f
#define B12 182.0f
#define B13 1.0f
#define MAXNORM 5.371920351148152f

__device__ __forceinline__ void mm3(const float a[9], const float b[9], float c[9]) {
#pragma unroll
  for (int i = 0; i < 3; ++i) {
#pragma unroll
    for (int j = 0; j < 3; ++j) {
      c[i * 3 + j] = fmaf(a[i * 3 + 0], b[0 + j],
                     fmaf(a[i * 3 + 1], b[3 + j],
                          a[i * 3 + 2] * b[6 + j]));
    }
  }
}

__global__ __launch_bounds__(TPB) void expm_loss_kernel(
    const float* __restrict__ mean, const float* __restrict__ var,
    const float* __restrict__ gt, float* __restrict__ partials) {
  __shared__ float sA[TPB * 9];
  __shared__ float sM[TPB * 3];
  __shared__ float sG[TPB * 3];
  const int tid = threadIdx.x;
  const long long base = (long long)blockIdx.x * TPB;

  // Coalesced global -> LDS staging (linear order).
#pragma unroll
  for (int k = 0; k < 9; ++k) sA[k * TPB + tid] = var[base * 9 + k * TPB + tid];
#pragma unroll
  for (int k = 0; k < 3; ++k) sM[k * TPB + tid] = mean[base * 3 + k * TPB + tid];
#pragma unroll
  for (int k = 0; k < 3; ++k) sG[k * TPB + tid] = gt[base * 3 + k * TPB + tid];
  __syncthreads();

  float A[9];
#pragma unroll
  for (int k = 0; k < 9; ++k) A[k] = sA[tid * 9 + k];  // stride-9: 2-way conflict = free
  const float d0 = sG[tid * 3 + 0] - sM[tid * 3 + 0];
  const float d1 = sG[tid * 3 + 1] - sM[tid * 3 + 1];
  const float d2 = sG[tid * 3 + 2] - sM[tid * 3 + 2];

  // --- scaling step: n_sq = max(0, ceil(log2(fro/MAXNORM))) ---
  float fro2 = 0.f;
#pragma unroll
  for (int k = 0; k < 9; ++k) fro2 = fmaf(A[k], A[k], fro2);
  const float fro = sqrtf(fro2);
  const float nsqf = fmaxf(0.0f, ceilf(log2f(fro * (1.0f / MAXNORM))));
  int nsq = (int)nsqf;
  nsq = nsq > 6 ? 6 : nsq;           // reference unrolls exactly 6 squarings
  const float scl = exp2f(-nsqf);    // exact power of two

  float As[9];
#pragma unroll
  for (int k = 0; k < 9; ++k) As[k] = A[k] * scl;

  // --- Pade-13 numerator/denominator ---
  float A2[9], A4[9], A6[9];
  mm3(As, As, A2);
  mm3(A2, A2, A4);
  mm3(A4, A2, A6);

  float W[9], T[9], U[9], V[9];
#pragma unroll
  for (int k = 0; k < 9; ++k)
    W[k] = fmaf(B13, A6[k], fmaf(B11, A4[k], B9 * A2[k]));
  mm3(A6, W, T);
#pragma unroll
  for (int k = 0; k < 9; ++k)
    T[k] = fmaf(B7, A6[k], fmaf(B5, A4[k], fmaf(B3, A2[k], T[k])));
  T[0] += B1; T[4] += B1; T[8] += B1;
  mm3(As, T, U);

#pragma unroll
  for (int k = 0; k < 9; ++k)
    W[k] = fmaf(B12, A6[k], fmaf(B10, A4[k], B8 * A2[k]));
  mm3(A6, W, V);
#pragma unroll
  for (int k = 0; k < 9; ++k)
    V[k] = fmaf(B6, A6[k], fmaf(B4, A4[k], fmaf(B2, A2[k], V[k])));
  V[0] += B0; V[4] += B0; V[8] += B0;

  // P = (U+V)/B0, Q = (V-U)/B0  -- scale by 1/B0 so det(Q) doesn't overflow fp32.
  const float s = 1.0f / B0;
  float P[9], Q[9];
#pragma unroll
  for (int k = 0; k < 9; ++k) {
    P[k] = (U[k] + V[k]) * s;
    Q[k] = (V[k] - U[k]) * s;
  }

  // R = Q^{-1} P via adjugate (Q ~ I + O(1), well-conditioned for ||A||<=MAXNORM)
  const float c00 = Q[4] * Q[8] - Q[5] * Q[7];
  const float c01 = Q[5] * Q[6] - Q[3] * Q[8];
  const float c02 = Q[3] * Q[7] - Q[4] * Q[6];
  const float c10 = Q[2] * Q[7] - Q[1] * Q[8];
  const float c11 = Q[0] * Q[8] - Q[2] * Q[6];
  const float c12 = Q[1] * Q[6] - Q[0] * Q[7];
  const float c20 = Q[1] * Q[5] - Q[2] * Q[4];
  const float c21 = Q[2] * Q[3] - Q[0] * Q[5];
  const float c22 = Q[0] * Q[4] - Q[1] * Q[3];
  const float detQ = Q[0] * c00 + Q[1] * c01 + Q[2] * c02;
  const float inv = 1.0f / detQ;
  const float Qi[9] = { c00 * inv, c10 * inv, c20 * inv,
                        c01 * inv, c11 * inv, c21 * inv,
                        c02 * inv, c12 * inv, c22 * inv };
  float R[9];
  mm3(Qi, P, R);

  // --- repeated squaring (runtime-bounded, almost always 0 iterations) ---
  for (int k = 0; k < nsq; ++k) {
    float R2[9];
    mm3(R, R, R2);
#pragma unroll
    for (int j = 0; j < 9; ++j) R[j] = R2[j];
  }

  // det of ORIGINAL A
  const float detA = A[0] * (A[4] * A[8] - A[5] * A[7])
                   - A[1] * (A[3] * A[8] - A[5] * A[6])
                   + A[2] * (A[3] * A[7] - A[4] * A[6]);

  // quad = d^T R d
  const float t0 = fmaf(R[0], d0, fmaf(R[1], d1, R[2] * d2));
  const float t1 = fmaf(R[3], d0, fmaf(R[4], d1, R[5] * d2));
  const float t2 = fmaf(R[6], d0, fmaf(R[7], d1, R[8] * d2));
  const float quad = fmaf(d0, t0, fmaf(d1, t1, d2 * t2));

  float val = 0.5f * (quad + detA);  // the /(n*bs) happens in the final reduce

  // --- fixed-tree block reduction (deterministic) ---
#pragma unroll
  for (int off = 32; off > 0; off >>= 1) val += __shfl_down(val, off, 64);
  __shared__ float wsum[TPB / 64];
  if ((tid & 63) == 0) wsum[tid >> 6] = val;
  __syncthreads();
  if (tid == 0) {
    float b = 0.f;
#pragma unroll
    for (int w = 0; w < TPB / 64; ++w) b += wsum[w];
    partials[blockIdx.x] = b;
  }
}

__global__ __launch_bounds__(256) void reduce_partials_kernel(
    const float* __restrict__ partials, int n, double inv_total,
    float* __restrict__ out) {
  double s = 0.0;
  for (int i = threadIdx.x; i < n; i += 256) s += (double)partials[i];
#pragma unroll
  for (int off = 32; off > 0; off >>= 1) s += __shfl_down(s, off, 64);
  __shared__ double ds[4];
  if ((threadIdx.x & 63) == 0) ds[threadIdx.x >> 6] = s;
  __syncthreads();
  if (threadIdx.x == 0)
    out[0] = (float)((ds[0] + ds[1] + ds[2] + ds[3]) * inv_total);
}

extern "C" void kernel_launch(void* const* d_in, const int* in_sizes, int n_in,
                              void* d_out, int out_size, void* d_ws, size_t ws_size,
                              hipStream_t stream) {
  const float* mean = (const float*)d_in[0];
  const float* var  = (const float*)d_in[1];
  const float* gt   = (const float*)d_in[2];
  const int nmat    = in_sizes[1] / 9;       // 1,572,864 (divisible by 256)
  const int nblocks = nmat / TPB;            // 6144
  float* partials   = (float*)d_ws;          // 6144 * 4 B = 24 KiB scratch

  expm_loss_kernel<<<nblocks, TPB, 0, stream>>>(mean, var, gt, partials);
  reduce_partials_kernel<<<1, 256, 0, stream>>>(partials, nblocks,
                                                1.0 / (double)nmat,
                                                (float*)d_out);
}

// Round 2
// 30.537 us; speedup vs baseline: 1.1116x; 1.1116x over previous
//
#include <hip/hip_runtime.h>

#define TPB 256

// Pade-13 coefficients (float32, matching reference `b = _PADE_B.astype(A.dtype)`)
#define B0  6.476475253248e+16f
#define B1  3.238237626624e+16f
#define B2  7.7717703038976e+15f
#define B3  1.1873537964288e+15f
#define B4  1.29060195264e+14f
#define B5  1.05594705216e+13f
#define B6  6.704425728e+11f
#define B7  3.352212864e+10f
#define B8  1.32324192e+9f
#define B9  4.08408e+7f
#define B10 9.6096e+5f
#define B11 1.638e+4f
#define B12 182.0f
#define B13 1.0f
#define MAXNORM 5.371920351148152f

__device__ __forceinline__ void mm3(const float a[9], const float b[9], float c[9]) {
#pragma unroll
  for (int i = 0; i < 3; ++i) {
#pragma unroll
    for (int j = 0; j < 3; ++j) {
      c[i * 3 + j] = fmaf(a[i * 3 + 0], b[0 + j],
                     fmaf(a[i * 3 + 1], b[3 + j],
                          a[i * 3 + 2] * b[6 + j]));
    }
  }
}

__global__ __launch_bounds__(TPB) void expm_loss_kernel(
    const float* __restrict__ mean, const float* __restrict__ var,
    const float* __restrict__ gt, float* __restrict__ partials) {
  // 256 matrices per block: var = 2304 f32 = 576 float4; mean/gt = 768 f32 = 192 float4 each.
  __shared__ float4 sA4[576];
  __shared__ float4 sM4[192];
  __shared__ float4 sG4[192];
  const float* sA = (const float*)sA4;
  const float* sM = (const float*)sM4;
  const float* sG = (const float*)sG4;
  const int tid = threadIdx.x;
  const long long base = (long long)blockIdx.x * TPB;

  // Coalesced float4 global -> LDS staging (16 B/lane).
  const float4* v4 = (const float4*)(var + base * 9);
  const float4* m4 = (const float4*)(mean + base * 3);
  const float4* g4 = (const float4*)(gt + base * 3);
  sA4[tid]       = v4[tid];
  sA4[tid + 256] = v4[tid + 256];
  if (tid < 64) sA4[tid + 512] = v4[tid + 512];
  if (tid < 192) { sM4[tid] = m4[tid]; sG4[tid] = g4[tid]; }
  __syncthreads();

  float A[9];
#pragma unroll
  for (int k = 0; k < 9; ++k) A[k] = sA[tid * 9 + k];  // stride-9: 2-way conflict = free
  const float d0 = sG[tid * 3 + 0] - sM[tid * 3 + 0];
  const float d1 = sG[tid * 3 + 1] - sM[tid * 3 + 1];
  const float d2 = sG[tid * 3 + 2] - sM[tid * 3 + 2];

  // --- scaling step: n_sq = max(0, ceil(0.5*log2(fro2) - log2(MAXNORM))) ---
  float fro2 = 0.f;
#pragma unroll
  for (int k = 0; k < 9; ++k) fro2 = fmaf(A[k], A[k], fro2);
  const float nsqf = fmaxf(0.0f, ceilf(fmaf(0.5f, __log2f(fro2), -2.4253625f)));
  int nsq = (int)nsqf;
  nsq = nsq > 6 ? 6 : nsq;           // reference unrolls exactly 6 squarings
  const float scl = exp2f(-nsqf);    // exact power of two

  float As[9];
#pragma unroll
  for (int k = 0; k < 9; ++k) As[k] = A[k] * scl;

  // --- Pade-13 numerator/denominator ---
  float A2[9], A4[9], A6[9];
  mm3(As, As, A2);
  mm3(A2, A2, A4);
  mm3(A4, A2, A6);

  float W[9], T[9], U[9], V[9];
#pragma unroll
  for (int k = 0; k < 9; ++k)
    W[k] = fmaf(B13, A6[k], fmaf(B11, A4[k], B9 * A2[k]));
  mm3(A6, W, T);
#pragma unroll
  for (int k = 0; k < 9; ++k)
    T[k] = fmaf(B7, A6[k], fmaf(B5, A4[k], fmaf(B3, A2[k], T[k])));
  T[0] += B1; T[4] += B1; T[8] += B1;
  mm3(As, T, U);

#pragma unroll
  for (int k = 0; k < 9; ++k)
    W[k] = fmaf(B12, A6[k], fmaf(B10, A4[k], B8 * A2[k]));
  mm3(A6, W, V);
#pragma unroll
  for (int k = 0; k < 9; ++k)
    V[k] = fmaf(B6, A6[k], fmaf(B4, A4[k], fmaf(B2, A2[k], V[k])));
  V[0] += B0; V[4] += B0; V[8] += B0;

  // P = (U+V)/B0, Q = (V-U)/B0  -- scale by 1/B0 so det(Q) doesn't overflow fp32.
  const float s = 1.0f / B0;
  float P[9], Q[9];
#pragma unroll
  for (int k = 0; k < 9; ++k) {
    P[k] = (U[k] + V[k]) * s;
    Q[k] = (V[k] - U[k]) * s;
  }

  // R = Q^{-1} P via adjugate (Q ~ I + O(1), well-conditioned for ||A||<=MAXNORM)
  const float c00 = Q[4] * Q[8] - Q[5] * Q[7];
  const float c01 = Q[5] * Q[6] - Q[3] * Q[8];
  const float c02 = Q[3] * Q[7] - Q[4] * Q[6];
  const float c10 = Q[2] * Q[7] - Q[1] * Q[8];
  const float c11 = Q[0] * Q[8] - Q[2] * Q[6];
  const float c12 = Q[1] * Q[6] - Q[0] * Q[7];
  const float c20 = Q[1] * Q[5] - Q[2] * Q[4];
  const float c21 = Q[2] * Q[3] - Q[0] * Q[5];
  const float c22 = Q[0] * Q[4] - Q[1] * Q[3];
  const float detQ = Q[0] * c00 + Q[1] * c01 + Q[2] * c02;
  const float inv = 1.0f / detQ;
  const float Qi[9] = { c00 * inv, c10 * inv, c20 * inv,
                        c01 * inv, c11 * inv, c21 * inv,
                        c02 * inv, c12 * inv, c22 * inv };
  float R[9];
  mm3(Qi, P, R);

  // --- repeated squaring (runtime-bounded, almost always 0 iterations) ---
  for (int k = 0; k < nsq; ++k) {
    float R2[9];
    mm3(R, R, R2);
#pragma unroll
    for (int j = 0; j < 9; ++j) R[j] = R2[j];
  }

  // det of ORIGINAL A
  const float detA = A[0] * (A[4] * A[8] - A[5] * A[7])
                   - A[1] * (A[3] * A[8] - A[5] * A[6])
                   + A[2] * (A[3] * A[7] - A[4] * A[6]);

  // quad = d^T R d
  const float t0 = fmaf(R[0], d0, fmaf(R[1], d1, R[2] * d2));
  const float t1 = fmaf(R[3], d0, fmaf(R[4], d1, R[5] * d2));
  const float t2 = fmaf(R[6], d0, fmaf(R[7], d1, R[8] * d2));
  const float quad = fmaf(d0, t0, fmaf(d1, t1, d2 * t2));

  float val = 0.5f * (quad + detA);  // the /(n*bs) happens in the final reduce

  // --- fixed-tree block reduction (deterministic) ---
#pragma unroll
  for (int off = 32; off > 0; off >>= 1) val += __shfl_down(val, off, 64);
  __shared__ float wsum[TPB / 64];
  if ((tid & 63) == 0) wsum[tid >> 6] = val;
  __syncthreads();
  if (tid == 0) {
    float b = 0.f;
#pragma unroll
    for (int w = 0; w < TPB / 64; ++w) b += wsum[w];
    partials[blockIdx.x] = b;
  }
}

#define RTPB 1024
__global__ __launch_bounds__(RTPB) void reduce_partials_kernel(
    const float* __restrict__ partials, int n, double inv_total,
    float* __restrict__ out) {
  double s = 0.0;
  for (int i = threadIdx.x; i < n; i += RTPB) s += (double)partials[i];
#pragma unroll
  for (int off = 32; off > 0; off >>= 1) s += __shfl_down(s, off, 64);
  __shared__ double ds[RTPB / 64];
  if ((threadIdx.x & 63) == 0) ds[threadIdx.x >> 6] = s;
  __syncthreads();
  if (threadIdx.x == 0) {
    double b = 0.0;
#pragma unroll
    for (int w = 0; w < RTPB / 64; ++w) b += ds[w];
    out[0] = (float)(b * inv_total);
  }
}

extern "C" void kernel_launch(void* const* d_in, const int* in_sizes, int n_in,
                              void* d_out, int out_size, void* d_ws, size_t ws_size,
                              hipStream_t stream) {
  const float* mean = (const float*)d_in[0];
  const float* var  = (const float*)d_in[1];
  const float* gt   = (const float*)d_in[2];
  const int nmat    = in_sizes[1] / 9;       // 1,572,864 (divisible by 256)
  const int nblocks = nmat / TPB;            // 6144
  float* partials   = (float*)d_ws;          // 6144 * 4 B = 24 KiB scratch

  expm_loss_kernel<<<nblocks, TPB, 0, stream>>>(mean, var, gt, partials);
  reduce_partials_kernel<<<1, RTPB, 0, stream>>>(partials, nblocks,
                                                 1.0 / (double)nmat,
                                                 (float*)d_out);
}

// Round 3
// 29.593 us; speedup vs baseline: 1.1471x; 1.0319x over previous
//
#include <hip/hip_runtime.h>

#define TPB 256

// Pade-13 coefficients (float32, matching reference `b = _PADE_B.astype(A.dtype)`)
#define B0  6.476475253248e+16f
#define B1  3.238237626624e+16f
#define B2  7.7717703038976e+15f
#define B3  1.1873537964288e+15f
#define B4  1.29060195264e+14f
#define B5  1.05594705216e+13f
#define B6  6.704425728e+11f
#define B7  3.352212864e+10f
#define B8  1.32324192e+9f
#define B9  4.08408e+7f
#define B10 9.6096e+5f
#define B11 1.638e+4f
#define B12 182.0f
#define B13 1.0f

__device__ __forceinline__ void mm3(const float a[9], const float b[9], float c[9]) {
#pragma unroll
  for (int i = 0; i < 3; ++i) {
#pragma unroll
    for (int j = 0; j < 3; ++j) {
      c[i * 3 + j] = fmaf(a[i * 3 + 0], b[0 + j],
                     fmaf(a[i * 3 + 1], b[3 + j],
                          a[i * 3 + 2] * b[6 + j]));
    }
  }
}

// One thread = one 3x3 matrix. No LDS staging, no barriers before the final
// reduce: 15 independent scalar loads per thread issue up-front; lane-stride
// 36B/12B patterns are L1-coalesced (same lines touched by adjacent lanes'
// instructions), so HBM traffic stays at the ideal 94.4 MB while 16 waves/CU
// (VGPR<=128 via launch_bounds) keep enough loads in flight to stream.
__global__ __launch_bounds__(TPB, 4) void expm_loss_kernel(
    const float* __restrict__ mean, const float* __restrict__ var,
    const float* __restrict__ gt, float* __restrict__ partials) {
  const int tid = threadIdx.x;
  const long long i = (long long)blockIdx.x * TPB + tid;

  const float* av = var + i * 9;
  const float* mv = mean + i * 3;
  const float* gv = gt + i * 3;

  float A[9];
#pragma unroll
  for (int k = 0; k < 9; ++k) A[k] = av[k];
  const float d0 = gv[0] - mv[0];
  const float d1 = gv[1] - mv[1];
  const float d2 = gv[2] - mv[2];

  // Consume A immediately so it is dead before the fat Pade section.
  const float detA = A[0] * (A[4] * A[8] - A[5] * A[7])
                   - A[1] * (A[3] * A[8] - A[5] * A[6])
                   + A[2] * (A[3] * A[7] - A[4] * A[6]);
  float fro2 = 0.f;
#pragma unroll
  for (int k = 0; k < 9; ++k) fro2 = fmaf(A[k], A[k], fro2);
  // n_sq = max(0, ceil(0.5*log2(fro2) - log2(MAXNORM)))
  const float nsqf = fmaxf(0.0f, ceilf(fmaf(0.5f, __log2f(fro2), -2.4253625f)));
  int nsq = (int)nsqf;
  nsq = nsq > 6 ? 6 : nsq;           // reference unrolls exactly 6 squarings
  const float scl = exp2f(-nsqf);    // exact power of two

  float As[9];
#pragma unroll
  for (int k = 0; k < 9; ++k) As[k] = A[k] * scl;

  // --- Pade-13 numerator/denominator ---
  float A2[9], A4[9], A6[9];
  mm3(As, As, A2);
  mm3(A2, A2, A4);
  mm3(A4, A2, A6);

  float W[9], T[9], U[9], V[9];
#pragma unroll
  for (int k = 0; k < 9; ++k)
    W[k] = fmaf(B13, A6[k], fmaf(B11, A4[k], B9 * A2[k]));
  mm3(A6, W, T);
#pragma unroll
  for (int k = 0; k < 9; ++k)
    T[k] = fmaf(B7, A6[k], fmaf(B5, A4[k], fmaf(B3, A2[k], T[k])));
  T[0] += B1; T[4] += B1; T[8] += B1;
  mm3(As, T, U);

#pragma unroll
  for (int k = 0; k < 9; ++k)
    W[k] = fmaf(B12, A6[k], fmaf(B10, A4[k], B8 * A2[k]));
  mm3(A6, W, V);
#pragma unroll
  for (int k = 0; k < 9; ++k)
    V[k] = fmaf(B6, A6[k], fmaf(B4, A4[k], fmaf(B2, A2[k], V[k])));
  V[0] += B0; V[4] += B0; V[8] += B0;

  // P = (U+V)/B0, Q = (V-U)/B0  -- 1/B0 scaling keeps det(Q) in fp32 range.
  const float s = 1.0f / B0;
  float P[9], Q[9];
#pragma unroll
  for (int k = 0; k < 9; ++k) {
    P[k] = (U[k] + V[k]) * s;
    Q[k] = (V[k] - U[k]) * s;
  }

  // R = Q^{-1} P via adjugate (Q ~ I + O(1), well-conditioned for ||A||<=MAXNORM)
  const float c00 = Q[4] * Q[8] - Q[5] * Q[7];
  const float c01 = Q[5] * Q[6] - Q[3] * Q[8];
  const float c02 = Q[3] * Q[7] - Q[4] * Q[6];
  const float c10 = Q[2] * Q[7] - Q[1] * Q[8];
  const float c11 = Q[0] * Q[8] - Q[2] * Q[6];
  const float c12 = Q[1] * Q[6] - Q[0] * Q[7];
  const float c20 = Q[1] * Q[5] - Q[2] * Q[4];
  const float c21 = Q[2] * Q[3] - Q[0] * Q[5];
  const float c22 = Q[0] * Q[4] - Q[1] * Q[3];
  const float detQ = Q[0] * c00 + Q[1] * c01 + Q[2] * c02;
  const float inv = 1.0f / detQ;
  const float Qi[9] = { c00 * inv, c10 * inv, c20 * inv,
                        c01 * inv, c11 * inv, c21 * inv,
                        c02 * inv, c12 * inv, c22 * inv };
  float R[9];
  mm3(Qi, P, R);

  // --- repeated squaring (runtime-bounded, almost always 0 iterations) ---
  for (int k = 0; k < nsq; ++k) {
    float R2[9];
    mm3(R, R, R2);
#pragma unroll
    for (int j = 0; j < 9; ++j) R[j] = R2[j];
  }

  // quad = d^T R d
  const float t0 = fmaf(R[0], d0, fmaf(R[1], d1, R[2] * d2));
  const float t1 = fmaf(R[3], d0, fmaf(R[4], d1, R[5] * d2));
  const float t2 = fmaf(R[6], d0, fmaf(R[7], d1, R[8] * d2));
  const float quad = fmaf(d0, t0, fmaf(d1, t1, d2 * t2));

  float val = 0.5f * (quad + detA);  // the /(n*bs) happens in the final reduce

  // --- fixed-tree block reduction (deterministic) ---
#pragma unroll
  for (int off = 32; off > 0; off >>= 1) val += __shfl_down(val, off, 64);
  __shared__ float wsum[TPB / 64];
  if ((tid & 63) == 0) wsum[tid >> 6] = val;
  __syncthreads();
  if (tid == 0) {
    float b = 0.f;
#pragma unroll
    for (int w = 0; w < TPB / 64; ++w) b += wsum[w];
    partials[blockIdx.x] = b;
  }
}

#define RTPB 1024
__global__ __launch_bounds__(RTPB) void reduce_partials_kernel(
    const float* __restrict__ partials, int n, double inv_total,
    float* __restrict__ out) {
  double s = 0.0;
  for (int i = threadIdx.x; i < n; i += RTPB) s += (double)partials[i];
#pragma unroll
  for (int off = 32; off > 0; off >>= 1) s += __shfl_down(s, off, 64);
  __shared__ double ds[RTPB / 64];
  if ((threadIdx.x & 63) == 0) ds[threadIdx.x >> 6] = s;
  __syncthreads();
  if (threadIdx.x == 0) {
    double b = 0.0;
#pragma unroll
    for (int w = 0; w < RTPB / 64; ++w) b += ds[w];
    out[0] = (float)(b * inv_total);
  }
}

extern "C" void kernel_launch(void* const* d_in, const int* in_sizes, int n_in,
                              void* d_out, int out_size, void* d_ws, size_t ws_size,
                              hipStream_t stream) {
  const float* mean = (const float*)d_in[0];
  const float* var  = (const float*)d_in[1];
  const float* gt   = (const float*)d_in[2];
  const int nmat    = in_sizes[1] / 9;       // 1,572,864 (divisible by 256)
  const int nblocks = nmat / TPB;            // 6144
  float* partials   = (float*)d_ws;          // 6144 * 4 B = 24 KiB scratch

  expm_loss_kernel<<<nblocks, TPB, 0, stream>>>(mean, var, gt, partials);
  reduce_partials_kernel<<<1, RTPB, 0, stream>>>(partials, nblocks,
                                                 1.0 / (double)nmat,
                                                 (float*)d_out);
}